// Round 14
// baseline (360.599 us; speedup 1.0000x reference)
//
#include <hip/hip_runtime.h>

#define BS_TOK 16384
#define HD 512
#define IDIM 2048
#define NE 8
#define RT_MAX 264            // max 128-row tiles after per-expert padding
#define CAP (RT_MAX * 128)    // 33792 slots

typedef unsigned short u16;
typedef unsigned int u32;
typedef __attribute__((ext_vector_type(8))) __bf16 bf16x8;
typedef __attribute__((ext_vector_type(4))) float f32x4;

__device__ __forceinline__ u16 f2bf(float f) {
  u32 u = __builtin_bit_cast(u32, f);
  u += 0x7fffu + ((u >> 16) & 1u);
  return (u16)(u >> 16);
}
__device__ __forceinline__ u16 f2bf_hw(float f) {
  u32 r;
  asm("v_cvt_pk_bf16_f32 %0, %1, %2" : "=v"(r) : "v"(f), "v"(f));
  return (u16)r;
}
__device__ __forceinline__ u32 pack2bf(float a, float b) {
  u32 r;
  asm("v_cvt_pk_bf16_f32 %0, %1, %2" : "=v"(r) : "v"(a), "v"(b));
  return r;
}
__device__ __forceinline__ float bflo(u32 u) { return __builtin_bit_cast(float, u << 16); }
__device__ __forceinline__ float bfhi(u32 u) { return __builtin_bit_cast(float, u & 0xffff0000u); }
// gelu tanh-approx via sigmoid; exp via v_exp_f32 (=2^x), log2e folded. Saturation-safe.
__device__ __forceinline__ float gelu_t(float v) {
  float t = v * (-2.302558f - 0.1029474f * v * v);
  return v * __builtin_amdgcn_rcpf(1.0f + __builtin_amdgcn_exp2f(t));
}
__device__ __forceinline__ void gload16(const u16* g, u16* l) {
  __builtin_amdgcn_global_load_lds((const __attribute__((address_space(1))) u16*)g,
                                   (__attribute__((address_space(3))) u16*)l, 16, 0, 0);
}

// Fused prep: blocks [0,4096) = 64x64-tile weight transpose (r12-proven);
// blocks [4096,8192) = router (r12-proven padded-LDS version), 4 tokens/block.
__global__ void k_prep(const float* __restrict__ W1, u16* __restrict__ W1T,
                       const float* __restrict__ W2, u16* __restrict__ W2T,
                       const float* __restrict__ x, const float* __restrict__ Wg,
                       const float* __restrict__ bg, int* __restrict__ top_e,
                       float* __restrict__ top_w, u32* __restrict__ counts,
                       float* __restrict__ Psum, u16* __restrict__ xb) {
  __shared__ float t[64][65];
  __shared__ float wg_s[HD * 9];
  __shared__ float Pp[NE];
  __shared__ u32 cnt[NE];
  int bid = blockIdx.x;
  int tid = threadIdx.x;
  if (bid < 4096) {
    int z = bid >> 8, tl = bid & 255;
    const float* in; u16* out; int Rin, Cin;
    if (z < NE) { in = W1; out = W1T; Rin = HD; Cin = IDIM; }
    else { in = W2; out = W2T; Rin = IDIM; Cin = HD; z -= NE; }
    size_t eb = (size_t)z * HD * IDIM;
    int tpr = Cin >> 6;
    int r0 = (tl / tpr) << 6, c0 = (tl % tpr) << 6;
    int row = tid >> 4, c4 = (tid & 15) << 2;
    #pragma unroll
    for (int i = 0; i < 4; ++i) {
      float4 v = *(const float4*)(in + eb + (size_t)(r0 + row + i * 16) * Cin + c0 + c4);
      t[row + i * 16][c4 + 0] = v.x; t[row + i * 16][c4 + 1] = v.y;
      t[row + i * 16][c4 + 2] = v.z; t[row + i * 16][c4 + 3] = v.w;
    }
    __syncthreads();
    int cc = tid >> 4, rr = (tid & 15) << 2;
    #pragma unroll
    for (int i = 0; i < 4; ++i) {
      int c = cc + i * 16;
      u32 lo = pack2bf(t[rr + 0][c], t[rr + 1][c]);
      u32 hi = pack2bf(t[rr + 2][c], t[rr + 3][c]);
      *(u32*)(out + eb + (size_t)(c0 + c) * Rin + r0 + rr)     = lo;
      *(u32*)(out + eb + (size_t)(c0 + c) * Rin + r0 + rr + 2) = hi;
    }
    return;
  }
  // ---- router ----
  if (tid < NE) { Pp[tid] = 0.f; cnt[tid] = 0; }
  for (int i = tid; i < HD * NE; i += 256) wg_s[(i >> 3) * 9 + (i & 7)] = Wg[i];
  __syncthreads();
  int wv = tid >> 6, lane = tid & 63;
  int tk = (bid - 4096) * 4 + wv;

  const float4* xr = (const float4*)(x + (size_t)tk * HD + lane * 8);
  float4 a = xr[0], b = xr[1];
  u32 p0 = pack2bf(a.x, a.y), p1 = pack2bf(a.z, a.w);
  u32 p2 = pack2bf(b.x, b.y), p3 = pack2bf(b.z, b.w);
  ((uint4*)(xb + (size_t)tk * HD))[lane] = make_uint4(p0, p1, p2, p3);

  float acc[NE];
  #pragma unroll
  for (int e = 0; e < NE; ++e) acc[e] = 0.f;
  #pragma unroll
  for (int j = 0; j < 8; ++j) {
    int h = lane + 64 * j;
    float xv = x[(size_t)tk * HD + h];
    const float* wrow = wg_s + h * 9;
    #pragma unroll
    for (int e = 0; e < NE; ++e) acc[e] += xv * wrow[e];
  }
  #pragma unroll
  for (int off = 32; off > 0; off >>= 1) {
    #pragma unroll
    for (int e = 0; e < NE; ++e) acc[e] += __shfl_down(acc[e], off);
  }
  if (lane == 0) {
    float lg[NE];
    #pragma unroll
    for (int e = 0; e < NE; ++e) lg[e] = acc[e] + bg[e];
    int i1 = 0; float m1 = lg[0];
    #pragma unroll
    for (int e = 1; e < NE; ++e) if (lg[e] > m1) { m1 = lg[e]; i1 = e; }
    int i2 = -1; float m2 = -1e30f;
    #pragma unroll
    for (int e = 0; e < NE; ++e) if (e != i1 && lg[e] > m2) { m2 = lg[e]; i2 = e; }
    float s = 0.f, p[NE];
    #pragma unroll
    for (int e = 0; e < NE; ++e) { p[e] = __expf(lg[e] - m1); s += p[e]; }
    float inv = 1.f / s;
    #pragma unroll
    for (int e = 0; e < NE; ++e) { p[e] *= inv; atomicAdd(&Pp[e], p[e]); }
    float denom = p[i1] + p[i2];
    top_e[2 * tk] = i1; top_e[2 * tk + 1] = i2;
    top_w[2 * tk] = p[i1] / denom; top_w[2 * tk + 1] = p[i2] / denom;
    atomicAdd(&cnt[i1], 1u); atomicAdd(&cnt[i2], 1u);
  }
  __syncthreads();
  if (tid < NE) { atomicAdd(&counts[tid], cnt[tid]); atomicAdd(&Psum[tid], Pp[tid]); }
}

// scatter with fused scan (unchanged, r12-proven)
__global__ void k_scatter(const int* __restrict__ top_e, const float* __restrict__ top_w,
                          const u32* __restrict__ counts, const float* __restrict__ Psum,
                          u32* __restrict__ pos_rel, int* __restrict__ perm_t,
                          u32* __restrict__ padoff, int* __restrict__ inv,
                          float* __restrict__ out) {
  __shared__ u32 po[NE];
  if (threadIdx.x == 0) {
    u32 off = 0; float loss = 0.f;
    for (int e = 0; e < NE; ++e) {
      po[e] = off;
      off += ((counts[e] + 127u) / 128u) * 128u;
      loss += ((float)counts[e] / (float)(BS_TOK * 2)) * (Psum[e] / (float)BS_TOK);
    }
    if (blockIdx.x == 0) {
      for (int e = 0; e < NE; ++e) padoff[e] = po[e];
      padoff[NE] = off;
      out[(size_t)BS_TOK * HD] = 0.01f * (float)NE * loss;
    }
  }
  __syncthreads();
  int g = blockIdx.x * 256 + threadIdx.x;
  int e = top_e[g]; float wgt = top_w[g];
  int lane = threadIdx.x & 63;
  #pragma unroll
  for (int ee = 0; ee < NE; ++ee) {
    unsigned long long m = __ballot(e == ee);
    if (e == ee) {
      int nb = __popcll(m & ((1ull << lane) - 1ull));
      int leader = __ffsll((unsigned long long)m) - 1;
      u32 base = 0;
      if (lane == leader) base = atomicAdd(&pos_rel[ee], (u32)__popcll(m));
      base = __shfl(base, leader);
      int slot = (int)(po[ee] + base) + nb;
      perm_t[slot] = g >> 1;
      inv[g] = slot;
    }
  }
}

// GEMM1: 128x256 / BK=64, 512 thr / 8 waves (2M x 4N -> wave tile 64x64).
// Phase-interleaved pipeline: per K-tile t (dbuf d=t&1), 2 phases of
// {ds_read frags | issue next-tile stage | lgkmcnt(0)+SB | setprio 16xMFMA};
// ONE vmcnt(0)+s_barrier per K-tile boundary (all outstanding loads = next
// tile's own 6, nothing deeper -> drain is exact; issue-early hides latency).
__global__ __launch_bounds__(512, 2) void k_gemm1(
    const u16* __restrict__ A, const u16* __restrict__ W,
    const float* __restrict__ bias, const int* __restrict__ perm_t,
    const u32* __restrict__ padoff, u16* __restrict__ C) {
  __shared__ u16 As[2][128 * 64];   // 32 KB
  __shared__ u16 Bs[2][256 * 64];   // 64 KB
  int nb = gridDim.x;               // 2112
  int b = blockIdx.x;
  int tile = (b & 7) * (nb >> 3) + (b >> 3);   // XCD-chunked
  int rt = tile >> 3, ct = tile & 7;           // 8 col-tiles of 256
  u32 s0 = (u32)rt * 128u;
  if (s0 >= padoff[NE]) return;
  int e = 0;
  #pragma unroll
  for (int k = 1; k < NE; ++k) e += (s0 >= padoff[k]) ? 1 : 0;

  int tid = threadIdx.x;
  int wv = tid >> 6, lane = tid & 63;
  int l15 = lane & 15, lg4 = lane >> 4;
  int wm = wv >> 2, wn = wv & 3;               // 2M x 4N

  int cb = (tid & 7) * 16;
  const u16* ap[2]; const u16* bp[4];
  #pragma unroll
  for (int i = 0; i < 2; ++i) {
    int row = (tid >> 3) + i * 64;
    int off = (cb ^ ((row & 7) << 4)) >> 1;
    ap[i] = A + (size_t)perm_t[s0 + row] * HD + off;
  }
  #pragma unroll
  for (int i = 0; i < 4; ++i) {
    int row = (tid >> 3) + i * 64;
    int off = (cb ^ ((row & 7) << 4)) >> 1;
    bp[i] = W + ((size_t)e * IDIM + ct * 256 + row) * HD + off;
  }

  int base_n = ct * 256 + wn * 64;
  f32x4 acc[4][4];
  #pragma unroll
  for (int fc = 0; fc < 4; ++fc) {
    float bv = bias[(size_t)e * IDIM + base_n + fc * 16 + l15];
    #pragma unroll
    for (int fr = 0; fr < 4; ++fr) acc[fr][fc] = f32x4{bv, bv, bv, bv};
  }

  // prologue: stage K-tile 0 into dbuf 0 (6 loads)
  #pragma unroll
  for (int i = 0; i < 2; ++i) gload16(ap[i], As[0] + tid * 8 + i * 4096);
  #pragma unroll
  for (int i = 0; i < 4; ++i) gload16(bp[i], Bs[0] + tid * 8 + i * 4096);
  asm volatile("s_waitcnt vmcnt(0)" ::: "memory");
  __builtin_amdgcn_sched_barrier(0);
  __builtin_amdgcn_s_barrier();
  __builtin_amdgcn_sched_barrier(0);

  for (int t = 0; t < 8; ++t) {
    int d = t & 1;
    const u16* Ab = As[d];
    const u16* Bb = Bs[d];
    u16* Ad = As[d ^ 1];
    u16* Bd = Bs[d ^ 1];
    int k0 = (t + 1) * 64;

    // ---- phase 0: A frags (held across both phases) + B fc 0,1 ----
    bf16x8 af[2][4], bfr[2][2];
    #pragma unroll
    for (int kk = 0; kk < 2; ++kk) {
      #pragma unroll
      for (int fr = 0; fr < 4; ++fr) {
        int ra = wm * 64 + fr * 16 + l15;
        af[kk][fr] = *(const bf16x8*)((const char*)Ab +
                     (ra * 128 + ((kk * 64 + lg4 * 16) ^ ((ra & 7) << 4))));
      }
      #pragma unroll
      for (int q = 0; q < 2; ++q) {
        int rb = wn * 64 + q * 16 + l15;
        bfr[kk][q] = *(const bf16x8*)((const char*)Bb +
                     (rb * 128 + ((kk * 64 + lg4 * 16) ^ ((rb & 7) << 4))));
      }
    }
    if (t + 1 < 8) {                 // stage units 0-3 of next K-tile
      #pragma unroll
      for (int i = 0; i < 2; ++i) gload16(ap[i] + k0, Ad + tid * 8 + i * 4096);
      #pragma unroll
      for (int i = 0; i < 2; ++i) gload16(bp[i] + k0, Bd + tid * 8 + i * 4096);
    }
    asm volatile("s_waitcnt lgkmcnt(0)" ::: "memory");
    __builtin_amdgcn_sched_barrier(0);                  // rule #18 fence
    __builtin_amdgcn_s_setprio(1);
    #pragma unroll
    for (int kk = 0; kk < 2; ++kk)
      #pragma unroll
      for (int fr = 0; fr < 4; ++fr)
        #pragma unroll
        for (int q = 0; q < 2; ++q)
          acc[fr][q] = __builtin_amdgcn_mfma_f32_16x16x32_bf16(af[kk][fr], bfr[kk][q], acc[fr][q], 0, 0, 0);
    __builtin_amdgcn_s_setprio(0);

    // ---- phase 1: B fc 2,3 ----
    #pragma unroll
    for (int kk = 0; kk < 2; ++kk) {
      #pragma unroll
      for (int q = 0; q < 2; ++q) {
        int rb = wn * 64 + (2 + q) * 16 + l15;
        bfr[kk][q] = *(const bf16x8*)((const char*)Bb +
                     (rb * 128 + ((kk * 64 + lg4 * 16) ^ ((rb & 7) << 4))));
      }
    }
    if (t + 1 < 8) {                 // stage units 4-5
      #pragma unroll
      for (int i = 2; i < 4; ++i) gload16(bp[i] + k0, Bd + tid * 8 + i * 4096);
    }
    asm volatile("s_waitcnt lgkmcnt(0)" ::: "memory");
    __builtin_amdgcn_sched_barrier(0);
    __builtin_amdgcn_s_setprio(1);
    #pragma unroll
    for (int kk = 0; kk < 2; ++kk)
      #pragma unroll
      for (int fr = 0; fr < 4; ++fr)
        #pragma unroll
        for (int q = 0; q < 2; ++q)
          acc[fr][2 + q] = __builtin_amdgcn_mfma_f32_16x16x32_bf16(af[kk][fr], bfr[kk][q], acc[fr][2 + q], 0, 0, 0);
    __builtin_amdgcn_s_setprio(0);

    // ---- K-tile boundary ----
    if (t + 1 < 8) {
      asm volatile("s_waitcnt vmcnt(0)" ::: "memory");  // next tile landed (exact)
      __builtin_amdgcn_sched_barrier(0);
      __builtin_amdgcn_s_barrier();                     // all waves done w/ dbuf d
      __builtin_amdgcn_sched_barrier(0);
    }
  }

  #pragma unroll
  for (int fr = 0; fr < 4; ++fr) {
    u32 mrow = s0 + wm * 64 + fr * 16 + lg4 * 4;
    #pragma unroll
    for (int rr = 0; rr < 4; ++rr) {
      #pragma unroll
      for (int fc = 0; fc < 4; ++fc) {
        float v = gelu_t(acc[fr][fc][rr]);   // bias already in acc
        C[(size_t)(mrow + rr) * IDIM + base_n + fc * 16 + l15] = f2bf_hw(v);
      }
    }
  }
}

// GEMM2: r12-proven 128x128 / BK=64 counted-vmcnt 2-phase, 256 thr.
template <int KSTEPS, int NCT, int NTOT>
__global__ __launch_bounds__(256, 2) void k_gemm2(
    const u16* __restrict__ A, int lda, const u16* __restrict__ W,
    const float* __restrict__ bias, const u32* __restrict__ padoff,
    u16* __restrict__ C) {
  __shared__ u16 As[2][8192], Bs[2][8192];
  int nb = gridDim.x;
  int b = blockIdx.x;
  int tile = (b & 7) * (nb >> 3) + (b >> 3);
  int rt = tile / NCT, ct = tile % NCT;
  u32 s0 = (u32)rt * 128u;
  if (s0 >= padoff[NE]) return;
  int e = 0;
  #pragma unroll
  for (int k = 1; k < NE; ++k) e += (s0 >= padoff[k]) ? 1 : 0;

  int tid = threadIdx.x;
  int wv = tid >> 6, lane = tid & 63;
  int l15 = lane & 15, lg4 = lane >> 4;
  int wr = wv >> 1, wc = wv & 1;

  int srow = tid >> 3;
  int cb = (tid & 7) * 16;
  int cbs = (cb ^ ((srow & 7) << 4)) >> 1;

  const u16* ap[4]; const u16* bp[4];
  #pragma unroll
  for (int i = 0; i < 4; ++i) {
    int r = i * 32 + srow;
    ap[i] = A + (size_t)(s0 + r) * lda + cbs;
    bp[i] = W + ((size_t)e * NTOT + ct * 128 + r) * (KSTEPS * 64) + cbs;
  }

  int base_n = ct * 128 + wc * 64;
  f32x4 acc[4][4];
  #pragma unroll
  for (int j = 0; j < 4; ++j) {
    float bv = bias[e * NTOT + base_n + j * 16 + l15];
    #pragma unroll
    for (int i = 0; i < 4; ++i) acc[i][j] = f32x4{bv, bv, bv, bv};
  }

  #pragma unroll
  for (int i = 0; i < 4; ++i) gload16(ap[i], As[0] + tid * 8 + i * 2048);
  #pragma unroll
  for (int i = 0; i < 4; ++i) gload16(bp[i], Bs[0] + tid * 8 + i * 2048);
  #pragma unroll
  for (int i = 0; i < 4; ++i) gload16(ap[i] + 64, As[1] + tid * 8 + i * 2048);
  #pragma unroll
  for (int i = 0; i < 4; ++i) gload16(bp[i] + 64, Bs[1] + tid * 8 + i * 2048);
  asm volatile("s_waitcnt vmcnt(8)" ::: "memory");
  __builtin_amdgcn_sched_barrier(0);
  __builtin_amdgcn_s_barrier();

  for (int ks = 0; ks < KSTEPS; ++ks) {
    int cur = ks & 1;
    const u16* Ab = As[cur];
    const u16* Bb = Bs[cur];
    bf16x8 af[2][4], bf[2][4];
    #pragma unroll
    for (int kk = 0; kk < 2; ++kk) {
      #pragma unroll
      for (int f = 0; f < 4; ++f) {
        int ra = wr * 64 + f * 16 + l15;
        af[kk][f] = *(const bf16x8*)((const char*)Ab +
                    (ra * 128 + ((kk * 64 + lg4 * 16) ^ ((ra & 7) << 4))));
        int rb = wc * 64 + f * 16 + l15;
        bf[kk][f] = *(const bf16x8*)((const char*)Bb +
                    (rb * 128 + ((kk * 64 + lg4 * 16) ^ ((rb & 7) << 4))));
      }
    }
    asm volatile("s_waitcnt lgkmcnt(0)" ::: "memory");
    __builtin_amdgcn_sched_barrier(0);
    __builtin_amdgcn_s_barrier();

    if (ks + 2 < KSTEPS) {
      int k0 = (ks + 2) * 64;
      #pragma unroll
      for (int i = 0; i < 4; ++i) gload16(ap[i] + k0, As[cur] + tid * 8 + i * 2048);
      #pragma unroll
      for (int i = 0; i < 4; ++i) gload16(bp[i] + k0, Bs[cur] + tid * 8 + i * 2048);
    }

    __builtin_amdgcn_s_setprio(1);
    #pragma unroll
    for (int kk = 0; kk < 2; ++kk)
      #pragma unroll
      for (int i = 0; i < 4; ++i)
        #pragma unroll
        for (int j = 0; j < 4; ++j)
          acc[i][j] = __builtin_amdgcn_mfma_f32_16x16x32_bf16(af[kk][i], bf[kk][j], acc[i][j], 0, 0, 0);
    __builtin_amdgcn_s_setprio(0);

    if (ks + 1 < KSTEPS) {
      if (ks + 2 < KSTEPS) {
        asm volatile("s_waitcnt vmcnt(8)" ::: "memory");
      } else {
        asm volatile("s_waitcnt vmcnt(0)" ::: "memory");
      }
      __builtin_amdgcn_sched_barrier(0);
      __builtin_amdgcn_s_barrier();
    }
  }

  #pragma unroll
  for (int i = 0; i < 4; ++i) {
    u32 mrow = s0 + wr * 64 + i * 16 + lg4 * 4;
    #pragma unroll
    for (int rr = 0; rr < 4; ++rr) {
      u32 m = mrow + rr;
      #pragma unroll
      for (int j = 0; j < 4; ++j)
        C[(size_t)m * NTOT + base_n + j * 16 + l15] = f2bf_hw(acc[i][j][rr]);
    }
  }
}

__global__ void k_final(const float* __restrict__ x, const u16* __restrict__ y,
                        const int* __restrict__ inv, const float* __restrict__ top_w,
                        float* __restrict__ out) {
  int tid = threadIdx.x;
  int t = blockIdx.x * 4 + (tid >> 6);
  int lane = tid & 63;
  int s0 = inv[2 * t], s1 = inv[2 * t + 1];
  float w0 = top_w[2 * t], w1 = top_w[2 * t + 1];
  size_t xo = (size_t)t * HD + lane * 8;
  float4 a = *(const float4*)(x + xo);
  float4 b = *(const float4*)(x + xo + 4);
  uint4 ya = *(const uint4*)(y + (size_t)s0 * HD + lane * 8);
  uint4 yb = *(const uint4*)(y + (size_t)s1 * HD + lane * 8);
  float4 o0, o1;
  o0.x = a.x + w0 * bflo(ya.x) + w1 * bflo(yb.x);
  o0.y = a.y + w0 * bfhi(ya.x) + w1 * bfhi(yb.x);
  o0.z = a.z + w0 * bflo(ya.y) + w1 * bflo(yb.y);
  o0.w = a.w + w0 * bfhi(ya.y) + w1 * bfhi(yb.y);
  o1.x = b.x + w0 * bflo(ya.z) + w1 * bflo(yb.z);
  o1.y = b.y + w0 * bfhi(ya.z) + w1 * bfhi(yb.z);
  o1.z = b.z + w0 * bflo(ya.w) + w1 * bflo(yb.w);
  o1.w = b.w + w0 * bfhi(ya.w) + w1 * bfhi(yb.w);
  *(float4*)(out + xo) = o0;
  *(float4*)(out + xo + 4) = o1;
}

extern "C" void kernel_launch(void* const* d_in, const int* in_sizes, int n_in,
                              void* d_out, int out_size, void* d_ws, size_t ws_size,
                              hipStream_t stream) {
  const float* x  = (const float*)d_in[0];
  const float* Wg = (const float*)d_in[1];
  const float* bg = (const float*)d_in[2];
  const float* W1 = (const float*)d_in[3];
  const float* b1 = (const float*)d_in[4];
  const float* W2 = (const float*)d_in[5];
  const float* b2 = (const float*)d_in[6];
  float* out = (float*)d_out;

  char* w = (char*)d_ws;
  u32* counts   = (u32*)(w + 0);
  u32* pos_rel  = (u32*)(w + 32);
  float* Psum   = (float*)(w + 64);
  u32* padoff   = (u32*)(w + 96);
  int* top_e    = (int*)(w + 256);
  float* top_w  = (float*)(w + 256 + 131072);
  int* invm     = (int*)(w + 256 + 2 * 131072);
  int* perm_t   = (int*)(w + 256 + 3 * 131072);
  u16* xb  = (u16*)(w + 663808);
  u16* W1T = (u16*)(w + 17441024);
  u16* W2T = (u16*)(w + 34218240);
  u16* h   = (u16*)(w + 50995456);
  u16* y   = (u16*)(w + 189407488);
  if (ws_size < 224010496ull) return;   // loud validation fail

  (void)hipMemsetAsync(w, 0, 663808, stream);
  k_prep<<<8192, 256, 0, stream>>>(W1, W1T, W2, W2T, x, Wg, bg,
                                   top_e, top_w, counts, Psum, xb);
  k_scatter<<<(BS_TOK * 2) / 256, 256, 0, stream>>>(top_e, top_w, counts, Psum,
                                                    pos_rel, perm_t, padoff, invm, out);
  k_gemm1<<<RT_MAX * 8, 512, 0, stream>>>(xb, W1T, b1, perm_t, padoff, h);
  k_gemm2<32, 4, HD><<<RT_MAX * 4, 256, 0, stream>>>(h, IDIM, W2T, b2, padoff, y);
  k_final<<<BS_TOK / 4, 256, 0, stream>>>(x, y, invm, top_w, out);
}

// Round 15
// 341.202 us; speedup vs baseline: 1.0569x; 1.0569x over previous
//
#include <hip/hip_runtime.h>

#define BS_TOK 16384
#define HD 512
#define IDIM 2048
#define NE 8
#define RT_MAX 264            // max 128-row tiles after per-expert padding
#define CAP (RT_MAX * 128)    // 33792 slots

typedef unsigned short u16;
typedef unsigned int u32;
typedef unsigned long long u64;
typedef __attribute__((ext_vector_type(8))) __bf16 bf16x8;
typedef __attribute__((ext_vector_type(4))) float f32x4;

__device__ __forceinline__ u16 f2bf(float f) {
  u32 u = __builtin_bit_cast(u32, f);
  u += 0x7fffu + ((u >> 16) & 1u);
  return (u16)(u >> 16);
}
__device__ __forceinline__ u16 f2bf_hw(float f) {
  u32 r;
  asm("v_cvt_pk_bf16_f32 %0, %1, %2" : "=v"(r) : "v"(f), "v"(f));
  return (u16)r;
}
__device__ __forceinline__ u32 pack2bf(float a, float b) {
  u32 r;
  asm("v_cvt_pk_bf16_f32 %0, %1, %2" : "=v"(r) : "v"(a), "v"(b));
  return r;
}
__device__ __forceinline__ float bflo(u32 u) { return __builtin_bit_cast(float, u << 16); }
__device__ __forceinline__ float bfhi(u32 u) { return __builtin_bit_cast(float, u & 0xffff0000u); }
// gelu tanh-approx via sigmoid; exp via v_exp_f32 (=2^x), log2e folded. Saturation-safe.
__device__ __forceinline__ float gelu_t(float v) {
  float t = v * (-2.302558f - 0.1029474f * v * v);
  return v * __builtin_amdgcn_rcpf(1.0f + __builtin_amdgcn_exp2f(t));
}
__device__ __forceinline__ void gload16(const u16* g, u16* l) {
  __builtin_amdgcn_global_load_lds((const __attribute__((address_space(1))) u16*)g,
                                   (__attribute__((address_space(3))) u16*)l, 16, 0, 0);
}

// Fused prep: blocks [0,4096) = 64x64 weight transpose (u64 coalesced stores);
// blocks [4096,8192) = router (r12-proven padded-LDS), 4 tokens/block.
__global__ void k_prep(const float* __restrict__ W1, u16* __restrict__ W1T,
                       const float* __restrict__ W2, u16* __restrict__ W2T,
                       const float* __restrict__ x, const float* __restrict__ Wg,
                       const float* __restrict__ bg, int* __restrict__ top_e,
                       float* __restrict__ top_w, u32* __restrict__ counts,
                       float* __restrict__ Psum, u16* __restrict__ xb) {
  __shared__ float t[64][65];
  __shared__ float wg_s[HD * 9];
  __shared__ float Pp[NE];
  __shared__ u32 cnt[NE];
  int bid = blockIdx.x;
  int tid = threadIdx.x;
  if (bid < 4096) {
    int z = bid >> 8, tl = bid & 255;
    const float* in; u16* out; int Rin, Cin;
    if (z < NE) { in = W1; out = W1T; Rin = HD; Cin = IDIM; }
    else { in = W2; out = W2T; Rin = IDIM; Cin = HD; z -= NE; }
    size_t eb = (size_t)z * HD * IDIM;
    int tpr = Cin >> 6;
    int r0 = (tl / tpr) << 6, c0 = (tl % tpr) << 6;
    int row = tid >> 4, c4 = (tid & 15) << 2;
    #pragma unroll
    for (int i = 0; i < 4; ++i) {
      float4 v = *(const float4*)(in + eb + (size_t)(r0 + row + i * 16) * Cin + c0 + c4);
      t[row + i * 16][c4 + 0] = v.x; t[row + i * 16][c4 + 1] = v.y;
      t[row + i * 16][c4 + 2] = v.z; t[row + i * 16][c4 + 3] = v.w;
    }
    __syncthreads();
    int cc = tid >> 4, rr = (tid & 15) << 2;
    #pragma unroll
    for (int i = 0; i < 4; ++i) {
      int c = cc + i * 16;
      u32 lo = pack2bf(t[rr + 0][c], t[rr + 1][c]);
      u32 hi = pack2bf(t[rr + 2][c], t[rr + 3][c]);
      u64 v = (u64)lo | ((u64)hi << 32);
      *(u64*)(out + eb + (size_t)(c0 + c) * Rin + r0 + rr) = v;   // 8B coalesced
    }
    return;
  }
  // ---- router ----
  if (tid < NE) { Pp[tid] = 0.f; cnt[tid] = 0; }
  for (int i = tid; i < HD * NE; i += 256) wg_s[(i >> 3) * 9 + (i & 7)] = Wg[i];
  __syncthreads();
  int wv = tid >> 6, lane = tid & 63;
  int tk = (bid - 4096) * 4 + wv;

  const float4* xr = (const float4*)(x + (size_t)tk * HD + lane * 8);
  float4 a = xr[0], b = xr[1];
  u32 p0 = pack2bf(a.x, a.y), p1 = pack2bf(a.z, a.w);
  u32 p2 = pack2bf(b.x, b.y), p3 = pack2bf(b.z, b.w);
  ((uint4*)(xb + (size_t)tk * HD))[lane] = make_uint4(p0, p1, p2, p3);

  float acc[NE];
  #pragma unroll
  for (int e = 0; e < NE; ++e) acc[e] = 0.f;
  #pragma unroll
  for (int j = 0; j < 8; ++j) {
    int h = lane + 64 * j;
    float xv = x[(size_t)tk * HD + h];
    const float* wrow = wg_s + h * 9;
    #pragma unroll
    for (int e = 0; e < NE; ++e) acc[e] += xv * wrow[e];
  }
  #pragma unroll
  for (int off = 32; off > 0; off >>= 1) {
    #pragma unroll
    for (int e = 0; e < NE; ++e) acc[e] += __shfl_down(acc[e], off);
  }
  if (lane == 0) {
    float lg[NE];
    #pragma unroll
    for (int e = 0; e < NE; ++e) lg[e] = acc[e] + bg[e];
    int i1 = 0; float m1 = lg[0];
    #pragma unroll
    for (int e = 1; e < NE; ++e) if (lg[e] > m1) { m1 = lg[e]; i1 = e; }
    int i2 = -1; float m2 = -1e30f;
    #pragma unroll
    for (int e = 0; e < NE; ++e) if (e != i1 && lg[e] > m2) { m2 = lg[e]; i2 = e; }
    float s = 0.f, p[NE];
    #pragma unroll
    for (int e = 0; e < NE; ++e) { p[e] = __expf(lg[e] - m1); s += p[e]; }
    float inv = 1.f / s;
    #pragma unroll
    for (int e = 0; e < NE; ++e) { p[e] *= inv; atomicAdd(&Pp[e], p[e]); }
    float denom = p[i1] + p[i2];
    top_e[2 * tk] = i1; top_e[2 * tk + 1] = i2;
    top_w[2 * tk] = p[i1] / denom; top_w[2 * tk + 1] = p[i2] / denom;
    atomicAdd(&cnt[i1], 1u); atomicAdd(&cnt[i2], 1u);
  }
  __syncthreads();
  if (tid < NE) { atomicAdd(&counts[tid], cnt[tid]); atomicAdd(&Psum[tid], Pp[tid]); }
}

// scatter with fused scan; perm_t stores g = (token<<1)|k (pads stay -1 sentinel).
__global__ void k_scatter(const int* __restrict__ top_e, const float* __restrict__ top_w,
                          const u32* __restrict__ counts, const float* __restrict__ Psum,
                          u32* __restrict__ pos_rel, int* __restrict__ perm_t,
                          u32* __restrict__ padoff, float* __restrict__ out) {
  __shared__ u32 po[NE];
  if (threadIdx.x == 0) {
    u32 off = 0; float loss = 0.f;
    for (int e = 0; e < NE; ++e) {
      po[e] = off;
      off += ((counts[e] + 127u) / 128u) * 128u;
      loss += ((float)counts[e] / (float)(BS_TOK * 2)) * (Psum[e] / (float)BS_TOK);
    }
    if (blockIdx.x == 0) {
      for (int e = 0; e < NE; ++e) padoff[e] = po[e];
      padoff[NE] = off;
      out[(size_t)BS_TOK * HD] = 0.01f * (float)NE * loss;
    }
  }
  __syncthreads();
  int g = blockIdx.x * 256 + threadIdx.x;   // (token,k) pair id
  int e = top_e[g];
  int lane = threadIdx.x & 63;
  #pragma unroll
  for (int ee = 0; ee < NE; ++ee) {
    unsigned long long m = __ballot(e == ee);
    if (e == ee) {
      int nb = __popcll(m & ((1ull << lane) - 1ull));
      int leader = __ffsll((unsigned long long)m) - 1;
      u32 base = 0;
      if (lane == leader) base = atomicAdd(&pos_rel[ee], (u32)__popcll(m));
      base = __shfl(base, leader);
      int slot = (int)(po[ee] + base) + nb;
      perm_t[slot] = g;
    }
  }
}

// 128x128 / BK=64 GEMM, counted-vmcnt 2-phase (r12-proven sync skeleton).
// GATHER: A row = token from perm_t g>>1 (pads clamp to 0).
// SCAT:   epilogue scatters rows to C[g*NTOT] (pads g<0 skipped).
template <int KSTEPS, int NCT, int NTOT, bool GATHER, bool ACT, bool SCAT>
__global__ __launch_bounds__(256, 2) void k_gemm(
    const u16* __restrict__ A, int lda, const u16* __restrict__ W,
    const float* __restrict__ bias, const int* __restrict__ perm_t,
    const u32* __restrict__ padoff, u16* __restrict__ C) {
  __shared__ u16 As[2][8192], Bs[2][8192];
  int nb = gridDim.x;
  int b = blockIdx.x;
  int tile = (b & 7) * (nb >> 3) + (b >> 3);   // XCD-chunked (nb % 8 == 0)
  int rt = tile / NCT, ct = tile % NCT;
  u32 s0 = (u32)rt * 128u;
  if (s0 >= padoff[NE]) return;
  int e = 0;
  #pragma unroll
  for (int k = 1; k < NE; ++k) e += (s0 >= padoff[k]) ? 1 : 0;

  int tid = threadIdx.x;
  int wv = tid >> 6, lane = tid & 63;
  int l15 = lane & 15, lg4 = lane >> 4;
  int wr = wv >> 1, wc = wv & 1;

  int srow = tid >> 3;
  int cb = (tid & 7) * 16;
  int cbs = (cb ^ ((srow & 7) << 4)) >> 1;     // pre-swizzled source elem offset

  const u16* ap[4]; const u16* bp[4];
  #pragma unroll
  for (int i = 0; i < 4; ++i) {
    int r = i * 32 + srow;
    int arow;
    if (GATHER) {
      int g = perm_t[s0 + r];
      arow = (g < 0 ? 0 : g) >> 1;
    } else {
      arow = (int)(s0 + r);
    }
    ap[i] = A + (size_t)arow * lda + cbs;
    bp[i] = W + ((size_t)e * NTOT + ct * 128 + r) * (KSTEPS * 64) + cbs;
  }

  int base_n = ct * 128 + wc * 64;
  f32x4 acc[4][4];
  #pragma unroll
  for (int j = 0; j < 4; ++j) {
    float bv = bias[e * NTOT + base_n + j * 16 + l15];
    #pragma unroll
    for (int i = 0; i < 4; ++i) acc[i][j] = f32x4{bv, bv, bv, bv};
  }

  // prologue: stage K-steps 0 and 1 (16 loads in flight)
  #pragma unroll
  for (int i = 0; i < 4; ++i) gload16(ap[i], As[0] + tid * 8 + i * 2048);
  #pragma unroll
  for (int i = 0; i < 4; ++i) gload16(bp[i], Bs[0] + tid * 8 + i * 2048);
  #pragma unroll
  for (int i = 0; i < 4; ++i) gload16(ap[i] + 64, As[1] + tid * 8 + i * 2048);
  #pragma unroll
  for (int i = 0; i < 4; ++i) gload16(bp[i] + 64, Bs[1] + tid * 8 + i * 2048);
  asm volatile("s_waitcnt vmcnt(8)" ::: "memory");
  __builtin_amdgcn_sched_barrier(0);
  __builtin_amdgcn_s_barrier();

  for (int ks = 0; ks < KSTEPS; ++ks) {
    int cur = ks & 1;
    const u16* Ab = As[cur];
    const u16* Bb = Bs[cur];
    bf16x8 af[2][4], bf[2][4];
    #pragma unroll
    for (int kk = 0; kk < 2; ++kk) {
      #pragma unroll
      for (int f = 0; f < 4; ++f) {
        int ra = wr * 64 + f * 16 + l15;
        af[kk][f] = *(const bf16x8*)((const char*)Ab +
                    (ra * 128 + ((kk * 64 + lg4 * 16) ^ ((ra & 7) << 4))));
        int rb = wc * 64 + f * 16 + l15;
        bf[kk][f] = *(const bf16x8*)((const char*)Bb +
                    (rb * 128 + ((kk * 64 + lg4 * 16) ^ ((rb & 7) << 4))));
      }
    }
    asm volatile("s_waitcnt lgkmcnt(0)" ::: "memory");
    __builtin_amdgcn_sched_barrier(0);                   // rule #18 fence
    __builtin_amdgcn_s_barrier();

    if (ks + 2 < KSTEPS) {
      int k0 = (ks + 2) * 64;
      #pragma unroll
      for (int i = 0; i < 4; ++i) gload16(ap[i] + k0, As[cur] + tid * 8 + i * 2048);
      #pragma unroll
      for (int i = 0; i < 4; ++i) gload16(bp[i] + k0, Bs[cur] + tid * 8 + i * 2048);
    }

    __builtin_amdgcn_s_setprio(1);
    #pragma unroll
    for (int kk = 0; kk < 2; ++kk)
      #pragma unroll
      for (int i = 0; i < 4; ++i)
        #pragma unroll
        for (int j = 0; j < 4; ++j)
          acc[i][j] = __builtin_amdgcn_mfma_f32_16x16x32_bf16(af[kk][i], bf[kk][j], acc[i][j], 0, 0, 0);
    __builtin_amdgcn_s_setprio(0);

    if (ks + 1 < KSTEPS) {
      if (ks + 2 < KSTEPS) {
        asm volatile("s_waitcnt vmcnt(8)" ::: "memory");
      } else {
        asm volatile("s_waitcnt vmcnt(0)" ::: "memory");
      }
      __builtin_amdgcn_sched_barrier(0);
      __builtin_amdgcn_s_barrier();
    }
  }

  #pragma unroll
  for (int i = 0; i < 4; ++i) {
    u32 mrow = s0 + wr * 64 + i * 16 + lg4 * 4;
    #pragma unroll
    for (int rr = 0; rr < 4; ++rr) {
      u32 m = mrow + rr;
      if (SCAT) {
        int g = perm_t[m];
        if (g >= 0) {
          #pragma unroll
          for (int j = 0; j < 4; ++j)
            C[(size_t)g * NTOT + base_n + j * 16 + l15] = f2bf_hw(acc[i][j][rr]);
        }
      } else {
        #pragma unroll
        for (int j = 0; j < 4; ++j) {
          float v = acc[i][j][rr];
          if (ACT) v = gelu_t(v);
          C[(size_t)m * NTOT + base_n + j * 16 + l15] = f2bf_hw(v);
        }
      }
    }
  }
}

// Fully-streaming final: out[t] = x[t] + w0*y2[2t] + w1*y2[2t+1]  (no gather)
__global__ void k_final(const float* __restrict__ x, const u16* __restrict__ y2,
                        const float* __restrict__ top_w, float* __restrict__ out) {
  int tid = threadIdx.x;
  int t = blockIdx.x * 4 + (tid >> 6);
  int lane = tid & 63;
  float w0 = top_w[2 * t], w1 = top_w[2 * t + 1];
  size_t xo = (size_t)t * HD + lane * 8;
  float4 a = *(const float4*)(x + xo);
  float4 b = *(const float4*)(x + xo + 4);
  uint4 ya = *(const uint4*)(y2 + (size_t)(2 * t) * HD + lane * 8);
  uint4 yb = *(const uint4*)(y2 + (size_t)(2 * t + 1) * HD + lane * 8);
  float4 o0, o1;
  o0.x = a.x + w0 * bflo(ya.x) + w1 * bflo(yb.x);
  o0.y = a.y + w0 * bfhi(ya.x) + w1 * bfhi(yb.x);
  o0.z = a.z + w0 * bflo(ya.y) + w1 * bflo(yb.y);
  o0.w = a.w + w0 * bfhi(ya.y) + w1 * bfhi(yb.y);
  o1.x = b.x + w0 * bflo(ya.z) + w1 * bflo(yb.z);
  o1.y = b.y + w0 * bfhi(ya.z) + w1 * bfhi(yb.z);
  o1.z = b.z + w0 * bflo(ya.w) + w1 * bflo(yb.w);
  o1.w = b.w + w0 * bfhi(ya.w) + w1 * bfhi(yb.w);
  *(float4*)(out + xo) = o0;
  *(float4*)(out + xo + 4) = o1;
}

extern "C" void kernel_launch(void* const* d_in, const int* in_sizes, int n_in,
                              void* d_out, int out_size, void* d_ws, size_t ws_size,
                              hipStream_t stream) {
  const float* x  = (const float*)d_in[0];
  const float* Wg = (const float*)d_in[1];
  const float* bg = (const float*)d_in[2];
  const float* W1 = (const float*)d_in[3];
  const float* b1 = (const float*)d_in[4];
  const float* W2 = (const float*)d_in[5];
  const float* b2 = (const float*)d_in[6];
  float* out = (float*)d_out;

  char* w = (char*)d_ws;
  u32* counts   = (u32*)(w + 0);
  u32* pos_rel  = (u32*)(w + 32);
  float* Psum   = (float*)(w + 64);
  u32* padoff   = (u32*)(w + 96);
  int* perm_t   = (int*)(w + 256);                 // 135168 B (0xFF sentinel)
  int* top_e    = (int*)(w + 135424);              // 131072 B
  float* top_w  = (float*)(w + 266496);            // 131072 B
  u16* xb  = (u16*)(w + 397568);                   // 16 MB
  u16* W1T = (u16*)(w + 17174784);                 // 16 MB
  u16* W2T = (u16*)(w + 33952000);                 // 16 MB
  u16* h   = (u16*)(w + 50729216);                 // 132 MB
  u16* y2  = (u16*)(w + 189141248);                // 32 MB (token-major)
  if (ws_size < 224010496ull) return;   // loud validation fail

  (void)hipMemsetAsync(w, 0, 256, stream);             // ctrl
  (void)hipMemsetAsync(w + 256, 0xFF, 135168, stream); // perm_t -> -1 sentinel
  k_prep<<<8192, 256, 0, stream>>>(W1, W1T, W2, W2T, x, Wg, bg,
                                   top_e, top_w, counts, Psum, xb);
  k_scatter<<<(BS_TOK * 2) / 256, 256, 0, stream>>>(top_e, top_w, counts, Psum,
                                                    pos_rel, perm_t, padoff, out);
  k_gemm<8, 16, IDIM, true, true, false><<<RT_MAX * 16, 256, 0, stream>>>(
      xb, HD, W1T, b1, perm_t, padoff, h);
  k_gemm<32, 4, HD, false, false, true><<<RT_MAX * 4, 256, 0, stream>>>(
      h, IDIM, W2T, b2, perm_t, padoff, y2);
  k_final<<<BS_TOK / 4, 256, 0, stream>>>(x, y2, top_w, out);
}